// Round 2
// baseline (82.112 us; speedup 1.0000x reference)
//
#include <hip/hip_runtime.h>

// (B,N,M,K) = (4,512,512,256): out[2048,256] = xq[2048,512] . wq[256,512]^T (int8)
// R7: single fused kernel, ZERO workspace usage.
//   Evidence: top-5 dispatches are all 256MiB ws-poison fills (41us @ 81% HBM peak).
//   Our kernels are under the fill; eliminate the quant dispatch + ws round-trip +
//   inter-kernel serialization entirely. Each wave quantizes its own fragments
//   from f32 and feeds MFMA directly. Correction sums via ones-operand MFMA.
constexpr int Mdim = 512;
constexpr int Kdim = 256;
constexpr int ROWS = 2048;

typedef int v4i __attribute__((ext_vector_type(4)));

__device__ __forceinline__ int qz(float v, float scale, float zp) {
    float q = rintf(v / scale + zp);          // matches jnp.round(t/scale + zp)
    q = fminf(fmaxf(q, -128.0f), 127.0f);
    return (int)q;
}

__device__ __forceinline__ int qp4(float4 f, float s, float zp) {
    int q0 = qz(f.x, s, zp), q1 = qz(f.y, s, zp);
    int q2 = qz(f.z, s, zp), q3 = qz(f.w, s, zp);
    return (q0 & 255) | ((q1 & 255) << 8) | ((q2 & 255) << 16) | ((q3 & 255) << 24);
}

// One wave per 16x32 output tile. 1024 blocks x 64 threads.
// A frag (HW-verified): lane l holds xq[r0+(l&15)][bytes kk*64+(l>>4)*16 ..+16)
// B frags: lane l holds wq[c+(l&15)][same bytes] for c = c0, c0+16
// D: col = c+(l&15), row = r0+(l>>4)*4+reg
// Sums: mfma(a, ones) -> D[r][c] = xsum[r] (acc[i] = xsum of the exact row the
// epilogue's reg i targets); mfma(ones, b) -> D[r][c] = wsum[c] (any reg).
__global__ __launch_bounds__(64) void fused_lutgemm_kernel(
        const float* __restrict__ x, const float* __restrict__ w,
        const float* __restrict__ x_scale, const float* __restrict__ x_zp,
        const float* __restrict__ w_scale, const float* __restrict__ w_zp,
        float* __restrict__ out) {
    const int lane  = threadIdx.x;
    const int group = lane >> 4;
    const int lo    = lane & 15;
    const int r0 = (blockIdx.x >> 3) * 16;   // 128 row-tiles
    const int c0 = (blockIdx.x & 7) * 32;    // 8 col-pair-tiles

    const float xs   = x_scale[0], xzpf = x_zp[0];
    const float wsf  = w_scale[0], wzpf = w_zp[0];

    // Per-lane fragment sources: 16 consecutive floats per (kk,group) slot.
    // Row has 128 float4s; kk advances 16 float4s; group offsets 4 float4s.
    const float4* xr  = (const float4*)(x + (size_t)(r0 + lo) * Mdim) + group * 4;
    const float4* wr0 = (const float4*)(w + (size_t)(c0 + lo) * Mdim) + group * 4;
    const float4* wr1 = (const float4*)(w + (size_t)(c0 + 16 + lo) * Mdim) + group * 4;

    v4i a[8], b0[8], b1[8];
    #pragma unroll
    for (int kk = 0; kk < 8; ++kk) {
        float4 f0 = xr[kk * 16 + 0], f1 = xr[kk * 16 + 1];
        float4 f2 = xr[kk * 16 + 2], f3 = xr[kk * 16 + 3];
        float4 g0 = wr0[kk * 16 + 0], g1 = wr0[kk * 16 + 1];
        float4 g2 = wr0[kk * 16 + 2], g3 = wr0[kk * 16 + 3];
        float4 h0 = wr1[kk * 16 + 0], h1 = wr1[kk * 16 + 1];
        float4 h2 = wr1[kk * 16 + 2], h3 = wr1[kk * 16 + 3];
        a[kk]  = (v4i){ qp4(f0, xs, xzpf),  qp4(f1, xs, xzpf),
                        qp4(f2, xs, xzpf),  qp4(f3, xs, xzpf) };
        b0[kk] = (v4i){ qp4(g0, wsf, wzpf), qp4(g1, wsf, wzpf),
                        qp4(g2, wsf, wzpf), qp4(g3, wsf, wzpf) };
        b1[kk] = (v4i){ qp4(h0, wsf, wzpf), qp4(h1, wsf, wzpf),
                        qp4(h2, wsf, wzpf), qp4(h3, wsf, wzpf) };
    }

    const v4i ones = {0x01010101, 0x01010101, 0x01010101, 0x01010101};
    v4i acc0  = {0, 0, 0, 0};
    v4i acc1  = {0, 0, 0, 0};
    v4i accxs = {0, 0, 0, 0};   // row sums of xq
    v4i accw0 = {0, 0, 0, 0};   // col sums of wq (c0..c0+15)
    v4i accw1 = {0, 0, 0, 0};   // col sums of wq (c0+16..c0+31)
    #pragma unroll
    for (int kk = 0; kk < 8; ++kk) {
        acc0  = __builtin_amdgcn_mfma_i32_16x16x64_i8(a[kk], b0[kk], acc0, 0, 0, 0);
        acc1  = __builtin_amdgcn_mfma_i32_16x16x64_i8(a[kk], b1[kk], acc1, 0, 0, 0);
        accxs = __builtin_amdgcn_mfma_i32_16x16x64_i8(a[kk], ones,   accxs, 0, 0, 0);
        accw0 = __builtin_amdgcn_mfma_i32_16x16x64_i8(ones,  b0[kk], accw0, 0, 0, 0);
        accw1 = __builtin_amdgcn_mfma_i32_16x16x64_i8(ones,  b1[kk], accw1, 0, 0, 0);
    }

    const float oscale    = xs * wsf;
    const float base_corr = (float)Mdim * xzpf * wzpf;
    const float corr0 = base_corr - xzpf * (float)accw0[0];
    const float corr1 = base_corr - xzpf * (float)accw1[0];

    #pragma unroll
    for (int i = 0; i < 4; ++i) {
        const int row = r0 + group * 4 + i;
        const float xc = wzpf * (float)accxs[i];
        float v0 = (float)acc0[i] - xc + corr0;
        float v1 = (float)acc1[i] - xc + corr1;
        out[(size_t)row * Kdim + c0 + lo]      = v0 * oscale;
        out[(size_t)row * Kdim + c0 + 16 + lo] = v1 * oscale;
    }
}

extern "C" void kernel_launch(void* const* d_in, const int* in_sizes, int n_in,
                              void* d_out, int out_size, void* d_ws, size_t ws_size,
                              hipStream_t stream) {
    const float* x       = (const float*)d_in[0];
    const float* w       = (const float*)d_in[1];
    // d_in[2] = lut: unused (lut[xi,wi] == signed(xi)*signed(wi))
    const float* x_scale = (const float*)d_in[3];
    const float* x_zp    = (const float*)d_in[4];
    const float* w_scale = (const float*)d_in[5];
    const float* w_zp    = (const float*)d_in[6];
    float* out = (float*)d_out;
    (void)d_ws; (void)ws_size;   // zero workspace usage

    fused_lutgemm_kernel<<<(ROWS / 16) * (Kdim / 32), 64, 0, stream>>>(
        x, w, x_scale, x_zp, w_scale, w_zp, out);
}

// Round 3
// 75.922 us; speedup vs baseline: 1.0815x; 1.0815x over previous
//
#include <hip/hip_runtime.h>

// (B,N,M,K) = (4,512,512,256): out[2048,256] = xq[2048,512] . wq[256,512]^T (int8)
// R8: single fused kernel, zero workspace, NON-redundant-ish quantization.
//   R7 post-mortem: fusing naively re-quantized w 128x and x 8x (25M exact f32
//   divisions) -> +10us. Fix: 64x32 block tile, 256 blocks (1/CU), 4 waves.
//   B-tile quantized ONCE per block into swizzled LDS (w redundancy 128->32),
//   A fragments global->reg with zero intra-block redundancy (x stays 8x).
constexpr int Mdim = 512;
constexpr int Kdim = 256;
constexpr int ROWS = 2048;

typedef int v4i __attribute__((ext_vector_type(4)));

__device__ __forceinline__ int qz(float v, float scale, float zp) {
    float q = rintf(v / scale + zp);          // matches jnp.round(t/scale + zp)
    q = fminf(fmaxf(q, -128.0f), 127.0f);
    return (int)q;
}

__device__ __forceinline__ int qp4(float4 f, float s, float zp) {
    int q0 = qz(f.x, s, zp), q1 = qz(f.y, s, zp);
    int q2 = qz(f.z, s, zp), q3 = qz(f.w, s, zp);
    return (q0 & 255) | ((q1 & 255) << 8) | ((q2 & 255) << 16) | ((q3 & 255) << 24);
}

// A frag (HW-verified): lane l holds xq[r][bytes kk*64+(l>>4)*16 ..+16), r = rowbase+(l&15)
// B frag: lane l holds wq[c+(l&15)][same bytes], c = c0 (b0) / c0+16 (b1)
// D: col = c+(l&15), row = rowbase+(l>>4)*4+reg
// LDS B layout: row-major 32 x 128 words, 16B granule g stored at g ^ (row&7)
// -> ds_read_b128 of a column-slice spreads 8 rows over all 32 banks (2-way, free).
__global__ __launch_bounds__(256) void fused_lutgemm_kernel(
        const float* __restrict__ x, const float* __restrict__ w,
        const float* __restrict__ x_scale, const float* __restrict__ x_zp,
        const float* __restrict__ w_scale, const float* __restrict__ w_zp,
        float* __restrict__ out) {
    __shared__ int bq[32 * 128];   // 16 KB packed int8 B-tile

    const int tid = threadIdx.x;
    const int r0 = (blockIdx.x >> 3) * 64;   // 32 row-blocks
    const int c0 = (blockIdx.x & 7) * 32;    // 8 col-blocks

    const float xs  = x_scale[0], xzpf = x_zp[0];
    const float wsf = w_scale[0], wzpf = w_zp[0];

    // --- stage B: quantize 32 w-rows once into LDS (each thread: 4 granules) ---
    {
        const int br = tid >> 3;              // 0..31 -> w row c0+br
        const int g0 = (tid & 7) * 4;         // granules g0..g0+3 (16 elems each)
        const float4* src = (const float4*)(w + (size_t)(c0 + br) * Mdim);
        #pragma unroll
        for (int j = 0; j < 4; ++j) {
            const int g = g0 + j;
            float4 f0 = src[g * 4 + 0], f1 = src[g * 4 + 1];
            float4 f2 = src[g * 4 + 2], f3 = src[g * 4 + 3];
            v4i q = { qp4(f0, wsf, wzpf), qp4(f1, wsf, wzpf),
                      qp4(f2, wsf, wzpf), qp4(f3, wsf, wzpf) };
            *(v4i*)&bq[br * 128 + (g ^ (br & 7)) * 4] = q;
        }
    }

    // --- A fragments: global -> quantize in-register (no intra-block redundancy) ---
    const int lane  = tid & 63;
    const int wv    = tid >> 6;               // wave 0..3 -> rows r0+16*wv..
    const int group = lane >> 4;
    const int lo    = lane & 15;
    const int arow  = r0 + wv * 16 + lo;
    const float4* xr = (const float4*)(x + (size_t)arow * Mdim) + group * 4;

    v4i a[8];
    #pragma unroll
    for (int kk = 0; kk < 8; ++kk) {
        float4 f0 = xr[kk * 16 + 0], f1 = xr[kk * 16 + 1];
        float4 f2 = xr[kk * 16 + 2], f3 = xr[kk * 16 + 3];
        a[kk] = (v4i){ qp4(f0, xs, xzpf), qp4(f1, xs, xzpf),
                       qp4(f2, xs, xzpf), qp4(f3, xs, xzpf) };
    }

    __syncthreads();

    // --- B fragments from swizzled LDS ---
    v4i b0[8], b1[8];
    #pragma unroll
    for (int kk = 0; kk < 8; ++kk) {
        const int g = kk * 4 + group;
        b0[kk] = *(const v4i*)&bq[lo * 128        + (g ^ (lo & 7)) * 4];
        b1[kk] = *(const v4i*)&bq[(16 + lo) * 128 + (g ^ (lo & 7)) * 4];
    }

    const v4i ones = {0x01010101, 0x01010101, 0x01010101, 0x01010101};
    v4i acc0  = {0, 0, 0, 0};
    v4i acc1  = {0, 0, 0, 0};
    v4i accxs = {0, 0, 0, 0};   // row sums of xq (reg i = epilogue row i)
    v4i accw0 = {0, 0, 0, 0};   // col sums of wq (c0..c0+15)
    v4i accw1 = {0, 0, 0, 0};   // col sums of wq (c0+16..c0+31)
    #pragma unroll
    for (int kk = 0; kk < 8; ++kk) {
        acc0  = __builtin_amdgcn_mfma_i32_16x16x64_i8(a[kk], b0[kk], acc0, 0, 0, 0);
        acc1  = __builtin_amdgcn_mfma_i32_16x16x64_i8(a[kk], b1[kk], acc1, 0, 0, 0);
        accxs = __builtin_amdgcn_mfma_i32_16x16x64_i8(a[kk], ones,   accxs, 0, 0, 0);
        accw0 = __builtin_amdgcn_mfma_i32_16x16x64_i8(ones,  b0[kk], accw0, 0, 0, 0);
        accw1 = __builtin_amdgcn_mfma_i32_16x16x64_i8(ones,  b1[kk], accw1, 0, 0, 0);
    }

    const float oscale    = xs * wsf;
    const float base_corr = (float)Mdim * xzpf * wzpf;
    const float corr0 = base_corr - xzpf * (float)accw0[0];
    const float corr1 = base_corr - xzpf * (float)accw1[0];

    #pragma unroll
    for (int i = 0; i < 4; ++i) {
        const int row = r0 + wv * 16 + group * 4 + i;
        const float xc = wzpf * (float)accxs[i];
        float v0 = (float)acc0[i] - xc + corr0;
        float v1 = (float)acc1[i] - xc + corr1;
        out[(size_t)row * Kdim + c0 + lo]      = v0 * oscale;
        out[(size_t)row * Kdim + c0 + 16 + lo] = v1 * oscale;
    }
}

extern "C" void kernel_launch(void* const* d_in, const int* in_sizes, int n_in,
                              void* d_out, int out_size, void* d_ws, size_t ws_size,
                              hipStream_t stream) {
    const float* x       = (const float*)d_in[0];
    const float* w       = (const float*)d_in[1];
    // d_in[2] = lut: unused (lut[xi,wi] == signed(xi)*signed(wi))
    const float* x_scale = (const float*)d_in[3];
    const float* x_zp    = (const float*)d_in[4];
    const float* w_scale = (const float*)d_in[5];
    const float* w_zp    = (const float*)d_in[6];
    float* out = (float*)d_out;
    (void)d_ws; (void)ws_size;   // zero workspace usage

    fused_lutgemm_kernel<<<(ROWS / 64) * (Kdim / 32), 256, 0, stream>>>(
        x, w, x_scale, x_zp, w_scale, w_zp, out);
}

// Round 4
// 72.033 us; speedup vs baseline: 1.1399x; 1.0540x over previous
//
#include <hip/hip_runtime.h>

// (B,N,M,K) = (4,512,512,256): out[2048,256] = xq[2048,512] · wq[256,512]^T (int8)
// R9 = verified R5 structure (72.0 us measured): quantize once to ws, then MFMA gemm.
//   Fusion experiments (R7: 82.1, R8: 75.9) proved redundant per-tile requantization
//   always loses vs quantize-once; two-kernel split is structurally optimal here.
//   R9 tweak: quant kernel 2304x64 -> 576x256 (4 waves/block, same per-wave math).
constexpr int Mdim = 512;
constexpr int Kdim = 256;
constexpr int ROWS = 2048;
constexpr int MW   = Mdim / 4;   // 128 packed int8-words per row

// ws layout (ints):
constexpr int XQ_OFF   = 0;                      // 2048 x 128 words, row-major
constexpr int WQ_OFF   = ROWS * MW;              // 262144: 256 x 128 words, row-major
constexpr int XSUM_OFF = WQ_OFF + Kdim * MW;     // 294912
constexpr int WSUM_OFF = XSUM_OFF + ROWS;        // 296960

typedef int v4i __attribute__((ext_vector_type(4)));

__device__ __forceinline__ int qz(float v, float scale, float zp) {
    float q = rintf(v / scale + zp);          // matches jnp.round(t/scale + zp)
    q = fminf(fmaxf(q, -128.0f), 127.0f);
    return (int)q;
}

__device__ __forceinline__ int pack4(int q0, int q1, int q2, int q3) {
    return (q0 & 255) | ((q1 & 255) << 8) | ((q2 & 255) << 16) | ((q3 & 255) << 24);
}

// 576 blocks x 256 threads; wave wv handles global row blockIdx.x*4+wv.
// Rows [0,2048): x; [2048,2304): w. 8 floats/lane, exact per-wave math of R5.
__global__ __launch_bounds__(256) void quant_kernel(
        const float* __restrict__ x, const float* __restrict__ w,
        const float* __restrict__ x_scale, const float* __restrict__ x_zp,
        const float* __restrict__ w_scale, const float* __restrict__ w_zp,
        int* __restrict__ ws) {
    const int lane = threadIdx.x & 63;
    const int wv   = threadIdx.x >> 6;
    const int grow = blockIdx.x * 4 + wv;
    const bool is_x = (grow < ROWS);
    const int row = is_x ? grow : (grow - ROWS);
    const float s  = is_x ? x_scale[0] : w_scale[0];
    const float zp = is_x ? x_zp[0]    : w_zp[0];
    const float* src = (is_x ? x : w) + (size_t)row * Mdim;

    const float4* src4 = (const float4*)src;
    float4 a = src4[lane * 2];
    float4 b = src4[lane * 2 + 1];

    int q0 = qz(a.x, s, zp), q1 = qz(a.y, s, zp), q2 = qz(a.z, s, zp), q3 = qz(a.w, s, zp);
    int q4 = qz(b.x, s, zp), q5 = qz(b.y, s, zp), q6 = qz(b.z, s, zp), q7 = qz(b.w, s, zp);

    const int base = (is_x ? XQ_OFF : WQ_OFF) + row * MW + 2 * lane;
    *(int2*)&ws[base] = make_int2(pack4(q0, q1, q2, q3), pack4(q4, q5, q6, q7));

    int sum = q0 + q1 + q2 + q3 + q4 + q5 + q6 + q7;
    #pragma unroll
    for (int off = 32; off > 0; off >>= 1) sum += __shfl_down(sum, off);
    if (lane == 0) ws[(is_x ? XSUM_OFF : WSUM_OFF) + row] = sum;
}

// One wave per 16x32 output tile. 1024 blocks x 64 threads. (verified at 72.0 us)
// A frag (HW-verified): lane l holds xq[r0+(l&15)][bytes kk*64+(l>>4)*16 ..+16)
// B frags: lane l holds wq[c+(l&15)][same bytes] for c = c0, c0+16
// D: col = c+(l&15), row = r0+(l>>4)*4+reg
__global__ __launch_bounds__(64) void mfma_gemm_kernel(
        const int* __restrict__ ws,
        const float* __restrict__ x_scale, const float* __restrict__ x_zp,
        const float* __restrict__ w_scale, const float* __restrict__ w_zp,
        float* __restrict__ out) {
    const int lane  = threadIdx.x;
    const int group = lane >> 4;
    const int lo    = lane & 15;
    const int r0 = (blockIdx.x >> 3) * 16;   // 128 row-tiles
    const int c0 = (blockIdx.x & 7) * 32;    // 8 col-pair-tiles

    const v4i* xa  = (const v4i*)&ws[XQ_OFF + (size_t)(r0 + lo) * MW];
    const v4i* wb0 = (const v4i*)&ws[WQ_OFF + (size_t)(c0 + lo) * MW];
    const v4i* wb1 = (const v4i*)&ws[WQ_OFF + (size_t)(c0 + 16 + lo) * MW];

    v4i a[8], b0[8], b1[8];
    #pragma unroll
    for (int kk = 0; kk < 8; ++kk) {         // 24 int4 loads in flight
        a[kk]  = xa[kk * 4 + group];
        b0[kk] = wb0[kk * 4 + group];
        b1[kk] = wb1[kk * 4 + group];
    }

    v4i acc0 = {0, 0, 0, 0};
    v4i acc1 = {0, 0, 0, 0};
    #pragma unroll
    for (int kk = 0; kk < 8; ++kk) {
        acc0 = __builtin_amdgcn_mfma_i32_16x16x64_i8(a[kk], b0[kk], acc0, 0, 0, 0);
        acc1 = __builtin_amdgcn_mfma_i32_16x16x64_i8(a[kk], b1[kk], acc1, 0, 0, 0);
    }

    const float xs = x_scale[0], xzpf = x_zp[0];
    const float wsf = w_scale[0], wzpf = w_zp[0];
    const float oscale = xs * wsf;
    const float base_corr = (float)Mdim * xzpf * wzpf;
    const float wsum0 = (float)ws[WSUM_OFF + c0 + lo];
    const float wsum1 = (float)ws[WSUM_OFF + c0 + 16 + lo];
    const float corr0 = base_corr - xzpf * wsum0;
    const float corr1 = base_corr - xzpf * wsum1;
    const v4i xs4 = *(const v4i*)&ws[XSUM_OFF + r0 + group * 4];  // 16B-aligned

    #pragma unroll
    for (int i = 0; i < 4; ++i) {
        const int row = r0 + group * 4 + i;
        const float xc = wzpf * (float)xs4[i];
        float v0 = (float)acc0[i] - xc + corr0;
        float v1 = (float)acc1[i] - xc + corr1;
        out[(size_t)row * Kdim + c0 + lo]      = v0 * oscale;
        out[(size_t)row * Kdim + c0 + 16 + lo] = v1 * oscale;
    }
}

extern "C" void kernel_launch(void* const* d_in, const int* in_sizes, int n_in,
                              void* d_out, int out_size, void* d_ws, size_t ws_size,
                              hipStream_t stream) {
    const float* x       = (const float*)d_in[0];
    const float* w       = (const float*)d_in[1];
    // d_in[2] = lut: unused (lut[xi,wi] == signed(xi)*signed(wi))
    const float* x_scale = (const float*)d_in[3];
    const float* x_zp    = (const float*)d_in[4];
    const float* w_scale = (const float*)d_in[5];
    const float* w_zp    = (const float*)d_in[6];
    float* out = (float*)d_out;
    int* ws = (int*)d_ws;

    quant_kernel<<<(ROWS + Kdim) / 4, 256, 0, stream>>>(x, w, x_scale, x_zp, w_scale, w_zp, ws);
    mfma_gemm_kernel<<<(ROWS / 16) * (Kdim / 32), 64, 0, stream>>>(
        ws, x_scale, x_zp, w_scale, w_zp, out);
}